// Round 10
// baseline (69.901 us; speedup 1.0000x reference)
//
#include <hip/hip_runtime.h>

typedef float f32x4 __attribute__((ext_vector_type(4)));

#define NBP 128   // partial-max blocks per table

// ---- pass 1: per-block partial maxes, f32x4 loads ----
// grid = 2*NBP blocks: first NBP -> tx partials, next NBP -> ty partials.
__global__ __launch_bounds__(256) void table_max_partial(
        const float* __restrict__ tx,
        const float* __restrict__ ty,
        int n4 /* n_table/4 */,
        float* __restrict__ px,
        float* __restrict__ py) {
    const bool isx = (int)blockIdx.x < NBP;
    const f32x4* t = (const f32x4*)(isx ? tx : ty);
    float* dst = isx ? px : py;
    const int b = isx ? blockIdx.x : blockIdx.x - NBP;
    const int stride = NBP * 256;
    float m = -INFINITY;
    for (int i = b * 256 + threadIdx.x; i < n4; i += stride) {
        const f32x4 v = t[i];
        m = fmaxf(m, fmaxf(fmaxf(v.x, v.y), fmaxf(v.z, v.w)));
    }
    #pragma unroll
    for (int off = 32; off > 0; off >>= 1)
        m = fmaxf(m, __shfl_down(m, off, 64));
    __shared__ float sm[4];
    const int lane = threadIdx.x & 63, wid = threadIdx.x >> 6;
    if (lane == 0) sm[wid] = m;
    __syncthreads();
    if (threadIdx.x == 0)
        dst[b] = fmaxf(fmaxf(sm[0], sm[1]), fmaxf(sm[2], sm[3]));
}

// ---- block-wide reduce of partials -> (sx, sy); NBP=128 <= blockDim ----
__device__ void reduce_scales(const float* __restrict__ px,
                              const float* __restrict__ py,
                              float& sx, float& sy) {
    float mx = (threadIdx.x < NBP) ? px[threadIdx.x] : -INFINITY;
    float my = (threadIdx.x < NBP) ? py[threadIdx.x] : -INFINITY;
    #pragma unroll
    for (int off = 32; off > 0; off >>= 1) {
        mx = fmaxf(mx, __shfl_down(mx, off, 64));
        my = fmaxf(my, __shfl_down(my, off, 64));
    }
    __shared__ float smx[4], smy[4];
    const int lane = threadIdx.x & 63, wid = threadIdx.x >> 6;
    if (lane == 0) { smx[wid] = mx; smy[wid] = my; }
    __syncthreads();
    sx = 0.1f / fmaxf(fmaxf(smx[0], smx[1]), fmaxf(smx[2], smx[3]));
    sy = 0.1f / fmaxf(fmaxf(smy[0], smy[1]), fmaxf(smy[2], smy[3]));
}

// ---- pass 2: fused scales-reduce + DIRECT gather (no intermediate table) ----
// Out f32x4 index i: row = i>>5, q = i&31 (stride % 32 == 0 -> q invariant).
// q<16 -> table_x half, j = q; else table_y half, j = q-16.
// out4[j] = s*(t[8j..8j+7] pairsum) + (fixed[8j..8j+7] pairsum)
//         = two f32x4 loads from table + two from fixed, combined.
__global__ __launch_bounds__(256) void gather_direct(
        const int* __restrict__ pos,
        const float* __restrict__ fixedt,
        const float* __restrict__ tx,
        const float* __restrict__ ty,
        const float* __restrict__ px,
        const float* __restrict__ py,
        f32x4* __restrict__ out, int total4) {
    float sx, sy;
    reduce_scales(px, py, sx, sy);

    const int stride = gridDim.x * blockDim.x;      // multiple of 32
    const int i0 = blockIdx.x * blockDim.x + threadIdx.x;
    const int  q    = i0 & 31;
    const bool isx  = (q < 16);
    const float s   = isx ? sx : sy;
    const int  j2   = (isx ? q : q - 16) * 2;       // source f32x4 slot (0,2,..,30)
    // pre-offset base pointers by the j-dependent part
    const f32x4* __restrict__ tab = (const f32x4*)(isx ? tx : ty) + j2;
    const f32x4* __restrict__ fx4 = (const f32x4*)fixedt + j2;
    const int  poff = isx ? 0 : 1;
    const int  rowstep = stride >> 5;

    int row = i0 >> 5;
    for (int i = i0; i < total4; i += stride, row += rowstep) {
        int p = pos[2 * row + poff];                // 16-lane-uniform broadcast
        if (p < 0) p = 1;
        const f32x4* tsrc = tab + p * 32;
        const f32x4* fsrc = fx4 + p * 32;
        const f32x4 t0 = tsrc[0];
        const f32x4 t1 = tsrc[1];
        const f32x4 f0 = fsrc[0];
        const f32x4 f1 = fsrc[1];
        f32x4 v;
        v.x = s * (t0.x + t0.y) + (f0.x + f0.y);
        v.y = s * (t0.z + t0.w) + (f0.z + f0.w);
        v.z = s * (t1.x + t1.y) + (f1.x + f1.y);
        v.w = s * (t1.z + t1.w) + (f1.z + f1.w);
        out[i] = v;
    }
}

extern "C" void kernel_launch(void* const* d_in, const int* in_sizes, int n_in,
                              void* d_out, int out_size, void* d_ws, size_t ws_size,
                              hipStream_t stream) {
    const int*   pos    = (const int*)  d_in[0];   // [16,512,32,2]
    const float* fixedt = (const float*)d_in[1];   // [table_len,128]
    const float* tx     = (const float*)d_in[2];
    const float* ty     = (const float*)d_in[3];
    f32x4* out = (f32x4*)d_out;

    const int n_table  = in_sizes[2];              // table_len * 128
    const int total4   = out_size >> 2;

    // ws layout: px[NBP], py[NBP]
    float* px = (float*)d_ws;
    float* py = px + NBP;

    table_max_partial<<<2 * NBP, 256, 0, stream>>>(tx, ty, n_table >> 2, px, py);
    gather_direct<<<2048, 256, 0, stream>>>(pos, fixedt, tx, ty, px, py,
                                            out, total4);
}

// Round 11
// 37.255 us; speedup vs baseline: 1.8763x; 1.8763x over previous
//
#include <hip/hip_runtime.h>

typedef float    f32x4 __attribute__((ext_vector_type(4)));
typedef _Float16 f16x4 __attribute__((ext_vector_type(4)));

#define NBP 128   // partial-max blocks per table

// ---- pass 1: per-block partial maxes, f32x4 loads ----
__global__ __launch_bounds__(256) void table_max_partial(
        const float* __restrict__ tx,
        const float* __restrict__ ty,
        int n4 /* n_table/4 */,
        float* __restrict__ px,
        float* __restrict__ py) {
    const bool isx = (int)blockIdx.x < NBP;
    const f32x4* t = (const f32x4*)(isx ? tx : ty);
    float* dst = isx ? px : py;
    const int b = isx ? blockIdx.x : blockIdx.x - NBP;
    const int stride = NBP * 256;
    float m = -INFINITY;
    for (int i = b * 256 + threadIdx.x; i < n4; i += stride) {
        const f32x4 v = t[i];
        m = fmaxf(m, fmaxf(fmaxf(v.x, v.y), fmaxf(v.z, v.w)));
    }
    #pragma unroll
    for (int off = 32; off > 0; off >>= 1)
        m = fmaxf(m, __shfl_down(m, off, 64));
    __shared__ float sm[4];
    const int lane = threadIdx.x & 63, wid = threadIdx.x >> 6;
    if (lane == 0) sm[wid] = m;
    __syncthreads();
    if (threadIdx.x == 0)
        dst[b] = fmaxf(fmaxf(sm[0], sm[1]), fmaxf(sm[2], sm[3]));
}

// ---- block-wide reduce of partials -> (sx, sy); NBP=128 <= blockDim ----
__device__ void reduce_scales(const float* __restrict__ px,
                              const float* __restrict__ py,
                              float& sx, float& sy) {
    float mx = (threadIdx.x < NBP) ? px[threadIdx.x] : -INFINITY;
    float my = (threadIdx.x < NBP) ? py[threadIdx.x] : -INFINITY;
    #pragma unroll
    for (int off = 32; off > 0; off >>= 1) {
        mx = fmaxf(mx, __shfl_down(mx, off, 64));
        my = fmaxf(my, __shfl_down(my, off, 64));
    }
    __shared__ float smx[4], smy[4];
    const int lane = threadIdx.x & 63, wid = threadIdx.x >> 6;
    if (lane == 0) { smx[wid] = mx; smy[wid] = my; }
    __syncthreads();
    sx = 0.1f / fmaxf(fmaxf(smx[0], smx[1]), fmaxf(smx[2], smx[3]));
    sy = 0.1f / fmaxf(fmaxf(smy[0], smy[1]), fmaxf(smy[2], smy[3]));
}

// ---- pass 2: build combined tables in FP16 (each [rows][64] f16) ----
// c[p][j] = s*(t[p][2j]+t[p][2j+1]) + (F[p][2j]+F[p][2j+1]), rounded to fp16.
__global__ __launch_bounds__(256) void build_kernel(
        const float* __restrict__ fixedt,
        const float* __restrict__ tx,
        const float* __restrict__ ty,
        const float* __restrict__ px,
        const float* __restrict__ py,
        f16x4* __restrict__ cx, f16x4* __restrict__ cy,
        int total16 /* rows*16 */) {
    float sx, sy;
    reduce_scales(px, py, sx, sy);
    const f32x4* fx4 = (const f32x4*)fixedt;
    const f32x4* tx4 = (const f32x4*)tx;
    const f32x4* ty4 = (const f32x4*)ty;
    const int stride = gridDim.x * blockDim.x;
    for (int i = blockIdx.x * blockDim.x + threadIdx.x; i < total16; i += stride) {
        const f32x4 f0 = fx4[2 * i], f1 = fx4[2 * i + 1];
        const f32x4 x0 = tx4[2 * i], x1 = tx4[2 * i + 1];
        const f32x4 y0 = ty4[2 * i], y1 = ty4[2 * i + 1];
        f16x4 cxv, cyv;
        cxv.x = (_Float16)(sx * (x0.x + x0.y) + (f0.x + f0.y));
        cxv.y = (_Float16)(sx * (x0.z + x0.w) + (f0.z + f0.w));
        cxv.z = (_Float16)(sx * (x1.x + x1.y) + (f1.x + f1.y));
        cxv.w = (_Float16)(sx * (x1.z + x1.w) + (f1.z + f1.w));
        cyv.x = (_Float16)(sy * (y0.x + y0.y) + (f0.x + f0.y));
        cyv.y = (_Float16)(sy * (y0.z + y0.w) + (f0.z + f0.w));
        cyv.z = (_Float16)(sy * (y1.x + y1.y) + (f1.x + f1.y));
        cyv.w = (_Float16)(sy * (y1.z + y1.w) + (f1.z + f1.w));
        cx[i] = cxv;
        cy[i] = cyv;
    }
}

// ---- pass 3: gather from fp16 tables, convert, store f32 (R8 shape) ----
// f32x4 index i: row = i>>5, q = i&31 (stride % 32 == 0 -> q invariant).
__global__ __launch_bounds__(256) void gather_kernel(
        const int* __restrict__ pos,
        const f16x4* __restrict__ cx,
        const f16x4* __restrict__ cy,
        f32x4* __restrict__ out, int total4) {
    const int stride = gridDim.x * blockDim.x;      // multiple of 32
    const int i0 = blockIdx.x * blockDim.x + threadIdx.x;
    const int  q    = i0 & 31;
    const bool isx  = (q < 16);
    const f16x4* __restrict__ tab = (isx ? cx : cy) + (isx ? q : q - 16);
    const int  poff = isx ? 0 : 1;
    const int  rowstep = stride >> 5;
    int row = i0 >> 5;
    for (int i = i0; i < total4; i += stride, row += rowstep) {
        int p = pos[2 * row + poff];                // 16-lane-uniform broadcast
        if (p < 0) p = 1;
        const f16x4 h = tab[p * 16];                // 8B load, 128B/half-row group
        f32x4 v;
        v.x = (float)h.x;  v.y = (float)h.y;
        v.z = (float)h.z;  v.w = (float)h.w;
        out[i] = v;
    }
}

extern "C" void kernel_launch(void* const* d_in, const int* in_sizes, int n_in,
                              void* d_out, int out_size, void* d_ws, size_t ws_size,
                              hipStream_t stream) {
    const int*   pos    = (const int*)  d_in[0];   // [16,512,32,2]
    const float* fixedt = (const float*)d_in[1];   // [table_len,128]
    const float* tx     = (const float*)d_in[2];
    const float* ty     = (const float*)d_in[3];
    f32x4* out = (f32x4*)d_out;

    const int n_table  = in_sizes[2];              // table_len * 128
    const int rows     = n_table >> 7;             // table_len
    const int total4   = out_size >> 2;

    // ws layout: px[NBP] f32, py[NBP] f32, then cx[rows*16] f16x4, cy[rows*16] f16x4
    float* px = (float*)d_ws;
    float* py = px + NBP;
    f16x4* cx = (f16x4*)(py + NBP);
    f16x4* cy = cx + (size_t)rows * 16;

    table_max_partial<<<2 * NBP, 256, 0, stream>>>(tx, ty, n_table >> 2, px, py);

    const int btot16 = rows * 16;
    build_kernel<<<(btot16 + 255) / 256, 256, 0, stream>>>(fixedt, tx, ty, px, py,
                                                           cx, cy, btot16);
    gather_kernel<<<2048, 256, 0, stream>>>(pos, (const f16x4*)cx, (const f16x4*)cy,
                                            out, total4);
}